// Round 9
// baseline (310.848 us; speedup 1.0000x reference)
//
#include <hip/hip_runtime.h>
#include <math.h>

#define D 128
#define MAXNORM 0.996f            // (1 - 4e-3)/sqrt(c), c = 1
#define MINNORM 1e-15f
#define ATCLAMP (1.0f - 1e-7f)

#define CHUNK 2048                // edges per sort block (8 per thread)
#define BSH   7                   // 128 nodes per bucket
#define MAXNB 1024                // supports N <= 131072 (problem: N = 100000)
#define SCAP2 5120                // ks3 LDS staging records (mean ~2046/bucket)

typedef unsigned int   u32;
typedef unsigned short u16;

typedef __attribute__((ext_vector_type(8))) _Float16 f16x8;
typedef __attribute__((ext_vector_type(2))) __fp16   h2raw;   // builtin return type
typedef __attribute__((ext_vector_type(4))) float f32x4;

__device__ __forceinline__ float wsum(float v) {
#pragma unroll
  for (int m = 32; m; m >>= 1) v += __shfl_xor(v, m);
  return v;
}
// 16-lane reduction (stays within a lane&48 group) — matches MFMA C-layout rows
__device__ __forceinline__ float rsum16(float v) {
#pragma unroll
  for (int m = 1; m <= 8; m <<= 1) v += __shfl_xor(v, m);
  return v;
}

__device__ __forceinline__ float frcp(float x) { return __builtin_amdgcn_rcpf(x); }

// fast artanh for x in [0, 1-1e-7]
__device__ __forceinline__ float fast_artanh(float x) {
  x = fminf(x, ATCLAMP);
  return 0.5f * __logf((1.0f + x) * frcp(1.0f - x));
}
// fast tanh for z >= 0
__device__ __forceinline__ float fast_tanh(float z) {
  float t = __expf(-2.0f * z);
  return (1.0f - t) * frcp(1.0f + t);
}

__device__ __forceinline__ float bflo(u32 u) { return __uint_as_float(u << 16); }
__device__ __forceinline__ float bfhi(u32 u) { return __uint_as_float(u & 0xffff0000u); }
__device__ __forceinline__ float bf2f(u16 h) { return __uint_as_float(((u32)h) << 16); }

// pack 2 f32 -> 2 f16 (RTZ, 1 instr v_cvt_pkrtz_f16_f32) — used for MFMA fragments
union H2U { h2raw h; u32 u; };
__device__ __forceinline__ u32 pkh(float a, float b) {
  H2U c; c.h = __builtin_amdgcn_cvt_pkrtz(a, b); return c.u;
}
union U2H { u32 u; _Float16 h[2]; };
union U4H8 { uint4 u; f16x8 h; };
__device__ __forceinline__ f16x8 as_h8(uint4 v) { U4H8 c; c.u = v; return c.h; }
__device__ __forceinline__ u16 f2h(float f) {        // f32 -> f16 bits (RNE)
  _Float16 h = (_Float16)f; return *(u16*)&h;
}

// ---- runtime dtype detection (wave-uniform; call before any divergence) ----
__device__ __forceinline__ bool detect_bf16(const u32* p) {
  float lo = fabsf(bflo(p[threadIdx.x & 63]));
  return (bool)__all(lo < 1.0f);
}
__device__ __forceinline__ bool detect_i64(const int* p) {
  return (bool)__all(p[2 * (threadIdx.x & 63) + 1] == 0);
}

// ====== K1: MFMA mobius_matvec + proj + mobius_add(bias) + proj + logmap0 ======
// FP16 compute plane (verified round 8). NEW: xt stored COLUMN-PERMUTED —
// true col c lives at u16 position p = (c&15)*8 + (c>>4). The C-fragment lane
// (qg,lc) holds cols lc+16t = positions lc*8..lc*8+7 -> ONE contiguous 16 B
// uint4 store per lane per row (full-line writes; kills the 5x write
// amplification + RFO fills seen in round 8: WRITE 124 MB -> 26 MB).
// kagg consumes the permuted layout directly (finalize is permutation-
// invariant); only its final store unpermutes via 4 shfls.
template<bool BF>
__device__ __forceinline__ void k1_body(const void* xv, const void* Wv,
                                        const void* bv, u16* xt, int N,
                                        uint4* Wh) {
  const int tid  = threadIdx.x;
  const int lane = tid & 63;
  const int wid  = tid >> 6;
  const int qg   = lane >> 4;   // k-block group 0..3
  const int lc   = lane & 15;   // col within 16-wide tile

  // stage W in fragment order (fp16): slot = (t*4+ks)*64 + l holds
  // W[(l&15)+16t, 32ks+8(l>>4) .. +8] as 8 fp16 (16B)
  for (int slot = tid; slot < 2048; slot += 256) {
    const int l = slot & 63, frag = slot >> 6;
    const int t = frag >> 2, ks = frag & 3;
    const int j  = (l & 15) + 16 * t;
    const int k0 = 32 * ks + 8 * (l >> 4);
    float f[8];
    if (BF) {
      uint4 v = ((const uint4*)Wv)[j * 16 + (k0 >> 3)];
      f[0] = bflo(v.x); f[1] = bfhi(v.x); f[2] = bflo(v.y); f[3] = bfhi(v.y);
      f[4] = bflo(v.z); f[5] = bfhi(v.z); f[6] = bflo(v.w); f[7] = bfhi(v.w);
    } else {
      const float* Wf = (const float*)Wv;
      float4 f0 = *(const float4*)(Wf + (size_t)j * D + k0);
      float4 f1 = *(const float4*)(Wf + (size_t)j * D + k0 + 4);
      f[0]=f0.x; f[1]=f0.y; f[2]=f0.z; f[3]=f0.w;
      f[4]=f1.x; f[5]=f1.y; f[6]=f1.z; f[7]=f1.w;
    }
    Wh[slot] = make_uint4(pkh(f[0],f[1]), pkh(f[2],f[3]),
                          pkh(f[4],f[5]), pkh(f[6],f[7]));
  }

  // hyp_bias fragment: bfr[t] = proj(expmap0(b))[lc + 16t]
  float bfr[8];
  float nb2 = 0.f;
#pragma unroll
  for (int t = 0; t < 8; ++t) {
    float v = BF ? bf2f(((const u16*)bv)[lc + 16 * t])
                 : ((const float*)bv)[lc + 16 * t];
    bfr[t] = v; nb2 += v * v;
  }
  nb2 = rsum16(nb2);
  float y2;
  {
    float nb = fmaxf(sqrtf(nb2), MINNORM);
    float s  = fast_tanh(nb) * frcp(nb);
    float n1 = s * nb;
    if (n1 > MAXNORM) s *= MAXNORM * frcp(n1);
#pragma unroll
    for (int t = 0; t < 8; ++t) bfr[t] *= s;
    y2 = s * s * nb2;
  }
  const bool bias_zero = (y2 == 0.0f);

  __syncthreads();

  const int T = (N + 15) >> 4;
  for (int tile = blockIdx.x * 4 + wid; tile < T; tile += gridDim.x * 4) {
    const int rbase = tile * 16;
    int rowA = rbase + lc; if (rowA >= N) rowA = N - 1;
    uint4 Ah[4];
    float xn2 = 0.f;
#pragma unroll
    for (int ks = 0; ks < 4; ++ks) {
      float f[8];
      if (BF) {
        uint4 v = ((const uint4*)((const u16*)xv + (size_t)rowA * D))[4 * ks + qg];
        f[0]=bflo(v.x); f[1]=bfhi(v.x); f[2]=bflo(v.y); f[3]=bfhi(v.y);
        f[4]=bflo(v.z); f[5]=bfhi(v.z); f[6]=bflo(v.w); f[7]=bfhi(v.w);
      } else {
        const float4* xr = (const float4*)((const float*)xv + (size_t)rowA * D);
        float4 f0 = xr[8 * ks + 2 * qg], f1 = xr[8 * ks + 2 * qg + 1];
        f[0]=f0.x; f[1]=f0.y; f[2]=f0.z; f[3]=f0.w;
        f[4]=f1.x; f[5]=f1.y; f[6]=f1.z; f[7]=f1.w;
      }
#pragma unroll
      for (int i = 0; i < 8; ++i) xn2 += f[i] * f[i];
      Ah[ks] = make_uint4(pkh(f[0],f[1]), pkh(f[2],f[3]),
                          pkh(f[4],f[5]), pkh(f[6],f[7]));
    }
    xn2 += __shfl_xor(xn2, 16);
    xn2 += __shfl_xor(xn2, 32);   // lane r holds ||x[rbase+r]||^2 (r = lane&15)

    f32x4 acc[8];
    const f32x4 zero = {0.f, 0.f, 0.f, 0.f};
#pragma unroll
    for (int t = 0; t < 8; ++t) acc[t] = zero;
#pragma unroll
    for (int ks = 0; ks < 4; ++ks) {
      f16x8 a = as_h8(Ah[ks]);
#pragma unroll
      for (int t = 0; t < 8; ++t) {
        f16x8 bh = as_h8(Wh[(t * 4 + ks) * 64 + lane]);
        acc[t] = __builtin_amdgcn_mfma_f32_16x16x32_f16(a, bh, acc[t], 0, 0, 0);
      }
    }

#pragma unroll
    for (int q = 0; q < 4; ++q) {
      const int row_off = qg * 4 + q;
      const int row = rbase + row_off;
      float xnq = fmaxf(sqrtf(__shfl(xn2, row_off)), MINNORM);
      float s2 = 0.f;
#pragma unroll
      for (int t = 0; t < 8; ++t) { float v = acc[t][q]; s2 += v * v; }
      s2 = rsum16(s2);
      float mxn = fmaxf(sqrtf(s2), MINNORM);
      float r = fast_tanh(mxn * frcp(xnq) * fast_artanh(xnq)) * frcp(mxn);
      float pn = r * mxn;
      if (pn > MAXNORM) { r *= MAXNORM * frcp(pn); pn = MAXNORM; }
      float h[8];
      float hn;
      if (bias_zero) {
#pragma unroll
        for (int t = 0; t < 8; ++t) h[t] = r * acc[t][q];
        hn = pn;
      } else {
        float xy = 0.f;
#pragma unroll
        for (int t = 0; t < 8; ++t) { h[t] = r * acc[t][q]; xy += h[t] * bfr[t]; }
        xy = rsum16(xy);
        float x2 = pn * pn;
        float ca = 1.f + 2.f * xy + y2;
        float cb = 1.f - x2;
        float id = frcp(fmaxf(1.f + 2.f * xy + x2 * y2, MINNORM));
        float s3 = 0.f;
#pragma unroll
        for (int t = 0; t < 8; ++t) { h[t] = (ca * h[t] + cb * bfr[t]) * id; s3 += h[t] * h[t]; }
        hn = fmaxf(sqrtf(rsum16(s3)), MINNORM);
      }
      float ps = (hn > MAXNORM) ? (MAXNORM * frcp(hn)) : 1.f;
      float np = fmaxf(hn * ps, MINNORM);
      float tsc = fast_artanh(np) * frcp(np) * ps;
      if (row < N) {
        // permuted store: positions lc*8..lc*8+7 = cols lc+16t, ONE uint4
        uint4 pk;
        pk.x = (u32)f2h(tsc * h[0]) | ((u32)f2h(tsc * h[1]) << 16);
        pk.y = (u32)f2h(tsc * h[2]) | ((u32)f2h(tsc * h[3]) << 16);
        pk.z = (u32)f2h(tsc * h[4]) | ((u32)f2h(tsc * h[5]) << 16);
        pk.w = (u32)f2h(tsc * h[6]) | ((u32)f2h(tsc * h[7]) << 16);
        *(uint4*)(xt + (size_t)row * D + lc * 8) = pk;
      }
    }
  }
}

extern "C" __global__ __launch_bounds__(256, 4)
void OriginHyperbolicGraphConvolution_38628935860614_kernel(
    const void* x, const void* W, const void* b, u16* xt, int* btot, int N) {
  __shared__ uint4 Wh[2048];   // 32 KB (single fp16 plane)
  if (blockIdx.x == 0)         // fold btot zeroing here (deletes k0 launch)
    for (int i = threadIdx.x; i < MAXNB; i += 256) btot[i] = 0;
  if (detect_bf16((const u32*)x)) k1_body<true >(x, W, b, xt, N, Wh);
  else                            k1_body<false>(x, W, b, xt, N, Wh);
}

// ====== ksA: SINGLE edge pass: chunk-local counting sort -> chunk-major ebuck ======
// Reads ei+ew once, LDS counting-sorts by coarse bucket, writes records
// chunk-major (fully coalesced), writes the per-chunk u16 bucket-offset row,
// and accumulates per-bucket totals via fire-and-forget global atomics.
// Record: x = src(17b)|dstin(7b)<<17, y = w bits.
extern "C" __global__ __launch_bounds__(256) void ksA(
    const int* ei, const void* ew, uint2* ebuck, u16* soffs, int* btot,
    int E, int N, int nb) {
  __shared__ int   hist[MAXNB];        // 4 KB
  __shared__ int   sArr[MAXNB + 1];    // 4 KB
  __shared__ int   psum[256];          // 1 KB
  __shared__ uint2 recs[CHUNK];        // 16 KB
  const bool i64 = detect_i64(ei);
  const bool bf  = detect_bf16((const u32*)ew);
  const int tid   = threadIdx.x;
  const int cbase = blockIdx.x * CHUNK;

  for (int i = tid; i < MAXNB; i += 256) hist[i] = 0;
  __syncthreads();

  int bkt[8], rank[8]; u32 px[8], wb[8]; bool val[8];
#pragma unroll
  for (int r = 0; r < 8; ++r) {
    const int e = cbase + r * 256 + tid;
    val[r] = false;
    if (e < E) {
      int dst, src;
      if (i64) {
        dst = (int)((const uint2*)ei)[(size_t)e].x;
        src = (int)((const uint2*)ei)[(size_t)E + e].x;
      } else {
        dst = ei[e]; src = ei[(size_t)E + e];
      }
      if ((unsigned)dst < (unsigned)N && (unsigned)src < (unsigned)N) {
        val[r] = true;
        bkt[r] = dst >> BSH;
        px[r]  = (u32)src | ((u32)(dst & ((1 << BSH) - 1)) << 17);
        float w;
        if (bf) w = bf2f(((const u16*)ew)[e]); else w = ((const float*)ew)[e];
        wb[r] = __float_as_uint(w);
        rank[r] = atomicAdd(&hist[bkt[r]], 1);
      }
    }
  }
  __syncthreads();

  // exclusive scan of hist -> sArr (256 threads x 4 bins)
  const int g0 = tid * 4;
  int loc[4], ts = 0;
#pragma unroll
  for (int i = 0; i < 4; ++i) { loc[i] = ts; ts += hist[g0 + i]; }
  psum[tid] = ts; __syncthreads();
#pragma unroll
  for (int off = 1; off < 256; off <<= 1) {
    int t = (tid >= off) ? psum[tid - off] : 0;
    __syncthreads();
    psum[tid] += t;
    __syncthreads();
  }
  const int excl = psum[tid] - ts;
#pragma unroll
  for (int i = 0; i < 4; ++i) sArr[g0 + i] = excl + loc[i];
  if (tid == 255) sArr[MAXNB] = psum[255];
  __syncthreads();

  // place into LDS in bucket-sorted order
#pragma unroll
  for (int r = 0; r < 8; ++r) if (val[r])
    recs[sArr[bkt[r]] + rank[r]] = make_uint2(px[r], wb[r]);
  __syncthreads();

  const int vcnt = sArr[MAXNB];
  // coalesced chunk-major write + per-chunk offset row + bucket totals
  for (int i = tid; i < vcnt; i += 256) ebuck[(size_t)cbase + i] = recs[i];
  u16* so = soffs + (size_t)blockIdx.x * (nb + 1);
  for (int b = tid; b <= nb; b += 256) so[b] = (u16)sArr[b];
  for (int b = tid; b < nb; b += 256) {
    const int len = sArr[b + 1] - sArr[b];
    if (len) atomicAdd(&btot[b], len);
  }
}

// ====== ks3: gather bucket's runs -> LDS -> node-sort -> esrt + offs2 ======
// Block per bucket. Computes its own exclusive prefix over btot (L2-resident).
// Phase 1: pull this bucket's ~2.6-record runs from all chunks into 40 KB LDS
// staging while node-histogramming. Phase 2: 128-scan -> offs2[node] =
// (start, count). Phase 3: scatter LDS -> esrt (L2-resident window), stripping
// dstin. Fallback (> SCAP2): two direct passes.
extern "C" __global__ __launch_bounds__(256) void ks3(
    const uint2* ebuck, const u16* soffs, const int* btot,
    uint2* esrt, uint2* offs2, int N, int nb, int nchunks) {
  __shared__ uint2 stage[SCAP2];       // 40 KB
  __shared__ int red[256];
  __shared__ int hist[128], sc[128], cur[128];
  __shared__ int lcur;
  const int tid = threadIdx.x;
  const int b = blockIdx.x;

  // exclusive prefix of btot over [0, b)
  int part = 0;
  for (int i = tid; i < b; i += 256) part += btot[i];
  red[tid] = part;
  if (tid < 128) hist[tid] = 0;
  if (tid == 0) lcur = 0;
  __syncthreads();
#pragma unroll
  for (int off = 128; off; off >>= 1) {
    if (tid < off) red[tid] += red[tid + off];
    __syncthreads();
  }
  const int s0  = red[0];
  const int cnt = btot[b];
  const int node0 = b << BSH;

  const bool fit = (cnt <= SCAP2);
  if (fit) {
    for (int c = tid; c < nchunks; c += 256) {
      const u16* so = soffs + (size_t)c * (nb + 1) + b;
      const int a = so[0], e = so[1];
      if (e > a) {
        const int base = atomicAdd(&lcur, e - a);
        for (int j = a; j < e; ++j) {
          const uint2 r = ebuck[(size_t)c * CHUNK + j];
          stage[base + (j - a)] = r;
          atomicAdd(&hist[(r.x >> 17) & 127], 1);
        }
      }
    }
  } else {
    for (int c = tid; c < nchunks; c += 256) {
      const u16* so = soffs + (size_t)c * (nb + 1) + b;
      for (int j = so[0]; j < so[1]; ++j)
        atomicAdd(&hist[(ebuck[(size_t)c * CHUNK + j].x >> 17) & 127], 1);
    }
  }
  __syncthreads();

  int v = 0;
  if (tid < 128) { v = hist[tid]; sc[tid] = v; }
  __syncthreads();
#pragma unroll
  for (int off = 1; off < 128; off <<= 1) {
    int t = (tid < 128 && tid >= off) ? sc[tid - off] : 0;
    __syncthreads();
    if (tid < 128) sc[tid] += t;
    __syncthreads();
  }
  if (tid < 128) {
    const int st = sc[tid] - v;
    cur[tid] = st;
    const int node = node0 + tid;
    if (node < N) offs2[node] = make_uint2((u32)(s0 + st), (u32)v);
  }
  __syncthreads();

  if (fit) {
    for (int i = tid; i < cnt; i += 256) {
      const uint2 r = stage[i];
      const int d = atomicAdd(&cur[(r.x >> 17) & 127], 1);
      esrt[s0 + d] = make_uint2(r.x & 0x1FFFFu, r.y);
    }
  } else {
    for (int c = tid; c < nchunks; c += 256) {
      const u16* so = soffs + (size_t)c * (nb + 1) + b;
      for (int j = so[0]; j < so[1]; ++j) {
        const uint2 r = ebuck[(size_t)c * CHUNK + j];
        const int d = atomicAdd(&cur[(r.x >> 17) & 127], 1);
        esrt[s0 + d] = make_uint2(r.x & 0x1FFFFu, r.y);
      }
    }
  }
}

// ====== kagg: gather-aggregate per node + fused finalize ======
// Wave per node, register accumulation, wave-uniform s_load edge records,
// 16-deep gather ILP. xt is fp16 PERMUTED (pos p = (c&15)*8 + (c>>4));
// accumulation + finalize are permutation-invariant; the final store
// unpermutes via 4 shfls (lane l needs true cols 2l, 2l+1).
extern "C" __global__ __launch_bounds__(256) void kagg(
    const uint2* offs2, const uint2* esrt, const u16* xt,
    void* out, const void* xdet, int N) {
  const bool bf = detect_bf16((const u32*)xdet);
  const int lane = threadIdx.x & 63;
  const int node = blockIdx.x * 4 + (threadIdx.x >> 6);
  if (node >= N) return;
  const uint2 oo = offs2[node];
  const int s0  = __builtin_amdgcn_readfirstlane((int)oo.x);
  const int cnt = __builtin_amdgcn_readfirstlane((int)oo.y);
  const uint2* ep = esrt + s0;
  const u32* xtw = (const u32*)xt;
  float a0 = 0.f, a1 = 0.f;      // permuted positions 2*lane, 2*lane+1
  int i = 0;
  for (; i + 16 <= cnt; i += 16) {
    uint2 e[16]; u32 u[16];
#pragma unroll
    for (int k = 0; k < 16; ++k) e[k] = ep[i + k];            // uniform (s_load)
#pragma unroll
    for (int k = 0; k < 16; ++k) u[k] = xtw[(e[k].x << 6) | lane];  // 16 in flight
#pragma unroll
    for (int k = 0; k < 16; ++k) {
      const float w = __uint_as_float(e[k].y);
      U2H c; c.u = u[k];
      a0 += w * (float)c.h[0];
      a1 += w * (float)c.h[1];
    }
  }
  for (; i + 4 <= cnt; i += 4) {
    uint2 e[4]; u32 u[4];
#pragma unroll
    for (int k = 0; k < 4; ++k) e[k] = ep[i + k];
#pragma unroll
    for (int k = 0; k < 4; ++k) u[k] = xtw[(e[k].x << 6) | lane];
#pragma unroll
    for (int k = 0; k < 4; ++k) {
      const float w = __uint_as_float(e[k].y);
      U2H c; c.u = u[k];
      a0 += w * (float)c.h[0];
      a1 += w * (float)c.h[1];
    }
  }
  for (; i < cnt; ++i) {
    const uint2 e = ep[i];
    const u32 u = xtw[(e.x << 6) | lane];
    const float w = __uint_as_float(e.y);
    U2H c; c.u = u;
    a0 += w * (float)c.h[0];
    a1 += w * (float)c.h[1];
  }
  // finalize: expmap0 -> proj -> logmap0 -> relu -> expmap0 -> proj
  // (all permutation-invariant: norms via wsum, elementwise scales/relu)
  float n = fmaxf(sqrtf(wsum(a0 * a0 + a1 * a1)), MINNORM);
  float tn = fast_tanh(n);
  float m = tn * frcp(n);
  if (tn > MAXNORM) { m *= MAXNORM * frcp(tn); tn = MAXNORM; }
  float nn = fmaxf(tn, MINNORM);
  m *= fast_artanh(nn) * frcp(nn);
  float tA = fmaxf(m * a0, 0.f), tB = fmaxf(m * a1, 0.f);
  float nr = fmaxf(sqrtf(wsum(tA * tA + tB * tB)), MINNORM);
  float t2 = fast_tanh(nr);
  float m2 = t2 * frcp(nr);
  if (t2 > MAXNORM) m2 *= MAXNORM * frcp(t2);
  float oA = m2 * tA, oB = m2 * tB;   // values for permuted positions 2l, 2l+1
  // unpermute: true col 2l lives at pos p0=(l&7)*16+(l>>3) -> lane p0>>1,
  // elem p0&1; true col 2l+1 at p0+8 -> lane+4, same elem. (lane-verified)
  const int ls = (lane & 7) * 8 + (lane >> 4);
  const int el = (lane >> 3) & 1;
  const float A0 = __shfl(oA, ls),     B0 = __shfl(oB, ls);
  const float A1 = __shfl(oA, ls + 4), B1 = __shfl(oB, ls + 4);
  const float v0 = el ? B0 : A0;
  const float v1 = el ? B1 : A1;
  if (bf) {
    // bf16 output (RNE)
    u32 ua = __float_as_uint(v0), ub = __float_as_uint(v1);
    u32 ra = (ua + 0x7fffu + ((ua >> 16) & 1u)) >> 16;
    u32 rb = (ub + 0x7fffu + ((ub >> 16) & 1u)) >> 16;
    ((u32*)out)[(size_t)node * 64 + lane] = ra | (rb << 16);
  } else {
    ((float2*)out)[(size_t)node * 64 + lane] = make_float2(v0, v1);
  }
}

extern "C" void kernel_launch(void* const* d_in, const int* in_sizes, int n_in,
                              void* d_out, int out_size, void* d_ws, size_t ws_size,
                              hipStream_t stream) {
  const void* x    = d_in[0];
  const void* W    = d_in[1];
  const void* bias = d_in[2];
  const int*  ei   = (const int*)d_in[3];
  const void* ew   = d_in[4];
  const int N = in_sizes[0] / D;
  const int E = in_sizes[4];
  const int nchunks = (E + CHUNK - 1) / CHUNK;
  const int nb      = (N + (1 << BSH) - 1) >> BSH;

  char* ws = (char*)d_ws;
  size_t off = 0;
  auto carve = [&](size_t bytes) { char* p = ws + off; off = (off + bytes + 255) & ~(size_t)255; return p; };
  u16*   xt    = (u16*)  carve((size_t)N * D * sizeof(u16));               // 25.6 MB
  uint2* ebuck = (uint2*)carve((size_t)nchunks * CHUNK * sizeof(uint2));   // 12.8 MB
  uint2* esrt  = (uint2*)carve((size_t)E * sizeof(uint2));                 // 12.8 MB
  u16*   soffs = (u16*)  carve((size_t)nchunks * (nb + 1) * sizeof(u16));  // 1.2 MB
  uint2* offs2 = (uint2*)carve((size_t)N * sizeof(uint2));                 // 0.8 MB
  int*   btot  = (int*)  carve((size_t)MAXNB * sizeof(int));               // 4 KB

  const int T  = (N + 15) / 16;
  const int g1 = min((T + 3) / 4, 1024);

  OriginHyperbolicGraphConvolution_38628935860614_kernel<<<g1, 256, 0, stream>>>(
      x, W, bias, xt, btot, N);
  ksA <<<nchunks, 256, 0, stream>>>(ei, ew, ebuck, soffs, btot, E, N, nb);
  ks3 <<<nb, 256, 0, stream>>>(ebuck, soffs, btot, esrt, offs2, N, nb, nchunks);
  kagg<<<(N + 3) / 4, 256, 0, stream>>>(offs2, esrt, xt, d_out, x, N);
}

// Round 10
// 269.277 us; speedup vs baseline: 1.1544x; 1.1544x over previous
//
#include <hip/hip_runtime.h>
#include <math.h>

#define D 128
#define MAXNORM 0.996f            // (1 - 4e-3)/sqrt(c), c = 1
#define MINNORM 1e-15f
#define ATCLAMP (1.0f - 1e-7f)

#define CHUNK 2048                // edges per sort block (8 per thread)
#define BSH   7                   // 128 nodes per bucket
#define MAXNB 1024                // supports N <= 131072 (problem: N = 100000)
#define SCAP2 5120                // ks3 LDS staging records (mean ~2046/bucket)

typedef unsigned int   u32;
typedef unsigned short u16;

typedef __attribute__((ext_vector_type(8))) _Float16 f16x8;
typedef __attribute__((ext_vector_type(2))) __fp16   h2raw;   // builtin return type
typedef __attribute__((ext_vector_type(4))) float f32x4;

__device__ __forceinline__ float wsum(float v) {
#pragma unroll
  for (int m = 32; m; m >>= 1) v += __shfl_xor(v, m);
  return v;
}
// 16-lane reduction (stays within a lane&48 group) — matches MFMA C-layout rows
__device__ __forceinline__ float rsum16(float v) {
#pragma unroll
  for (int m = 1; m <= 8; m <<= 1) v += __shfl_xor(v, m);
  return v;
}

__device__ __forceinline__ float frcp(float x) { return __builtin_amdgcn_rcpf(x); }

// fast artanh for x in [0, 1-1e-7]
__device__ __forceinline__ float fast_artanh(float x) {
  x = fminf(x, ATCLAMP);
  return 0.5f * __logf((1.0f + x) * frcp(1.0f - x));
}
// fast tanh for z >= 0
__device__ __forceinline__ float fast_tanh(float z) {
  float t = __expf(-2.0f * z);
  return (1.0f - t) * frcp(1.0f + t);
}

__device__ __forceinline__ float bflo(u32 u) { return __uint_as_float(u << 16); }
__device__ __forceinline__ float bfhi(u32 u) { return __uint_as_float(u & 0xffff0000u); }
__device__ __forceinline__ float bf2f(u16 h) { return __uint_as_float(((u32)h) << 16); }

// pack 2 f32 -> 2 f16 (RTZ, 1 instr v_cvt_pkrtz_f16_f32) — used for MFMA fragments
union H2U { h2raw h; u32 u; };
__device__ __forceinline__ u32 pkh(float a, float b) {
  H2U c; c.h = __builtin_amdgcn_cvt_pkrtz(a, b); return c.u;
}
union U2H { u32 u; _Float16 h[2]; };
union U4H8 { uint4 u; f16x8 h; };
__device__ __forceinline__ f16x8 as_h8(uint4 v) { U4H8 c; c.u = v; return c.h; }
__device__ __forceinline__ u16 f2h(float f) {        // f32 -> f16 bits (RNE)
  _Float16 h = (_Float16)f; return *(u16*)&h;
}

// ---- runtime dtype detection (wave-uniform; call before any divergence) ----
__device__ __forceinline__ bool detect_bf16(const u32* p) {
  float lo = fabsf(bflo(p[threadIdx.x & 63]));
  return (bool)__all(lo < 1.0f);
}
__device__ __forceinline__ bool detect_i64(const int* p) {
  return (bool)__all(p[2 * (threadIdx.x & 63) + 1] == 0);
}

// ====== K1: MFMA mobius_matvec + proj + mobius_add(bias) + proj + logmap0 ======
// FP16 compute plane (verified round 8/9), permuted xt store (verified round 9).
// LAUNCH REVERTED to round-5 semantics: ONE 16-row tile per wave, grid =
// ceil(T/4), block exits after its tile — the capped persistent grid of rounds
// 8/9 left the 0.53-phase tail at half occupancy with no block backfill
// (2154/4096 waves owned 2 tiles). 32 KB LDS -> 4 blocks/CU resident.
// C layout (m89-verified): col = lane&15, row = (lane>>4)*4 + reg.
// xt layout: true col c at u16 position (c&15)*8 + (c>>4) -> one uint4/lane/row.
template<bool BF>
__device__ __forceinline__ void k1_body(const void* xv, const void* Wv,
                                        const void* bv, u16* xt, int N,
                                        uint4* Wh) {
  const int tid  = threadIdx.x;
  const int lane = tid & 63;
  const int wid  = tid >> 6;
  const int qg   = lane >> 4;   // k-block group 0..3
  const int lc   = lane & 15;   // col within 16-wide tile

  // stage W in fragment order (fp16): slot = (t*4+ks)*64 + l holds
  // W[(l&15)+16t, 32ks+8(l>>4) .. +8] as 8 fp16 (16B)
  for (int slot = tid; slot < 2048; slot += 256) {
    const int l = slot & 63, frag = slot >> 6;
    const int t = frag >> 2, ks = frag & 3;
    const int j  = (l & 15) + 16 * t;
    const int k0 = 32 * ks + 8 * (l >> 4);
    float f[8];
    if (BF) {
      uint4 v = ((const uint4*)Wv)[j * 16 + (k0 >> 3)];
      f[0] = bflo(v.x); f[1] = bfhi(v.x); f[2] = bflo(v.y); f[3] = bfhi(v.y);
      f[4] = bflo(v.z); f[5] = bfhi(v.z); f[6] = bflo(v.w); f[7] = bfhi(v.w);
    } else {
      const float* Wf = (const float*)Wv;
      float4 f0 = *(const float4*)(Wf + (size_t)j * D + k0);
      float4 f1 = *(const float4*)(Wf + (size_t)j * D + k0 + 4);
      f[0]=f0.x; f[1]=f0.y; f[2]=f0.z; f[3]=f0.w;
      f[4]=f1.x; f[5]=f1.y; f[6]=f1.z; f[7]=f1.w;
    }
    Wh[slot] = make_uint4(pkh(f[0],f[1]), pkh(f[2],f[3]),
                          pkh(f[4],f[5]), pkh(f[6],f[7]));
  }

  // hyp_bias fragment: bfr[t] = proj(expmap0(b))[lc + 16t]
  float bfr[8];
  float nb2 = 0.f;
#pragma unroll
  for (int t = 0; t < 8; ++t) {
    float v = BF ? bf2f(((const u16*)bv)[lc + 16 * t])
                 : ((const float*)bv)[lc + 16 * t];
    bfr[t] = v; nb2 += v * v;
  }
  nb2 = rsum16(nb2);
  float y2;
  {
    float nb = fmaxf(sqrtf(nb2), MINNORM);
    float s  = fast_tanh(nb) * frcp(nb);
    float n1 = s * nb;
    if (n1 > MAXNORM) s *= MAXNORM * frcp(n1);
#pragma unroll
    for (int t = 0; t < 8; ++t) bfr[t] *= s;
    y2 = s * s * nb2;
  }
  const bool bias_zero = (y2 == 0.0f);

  __syncthreads();

  const int T = (N + 15) >> 4;
  const int tile = blockIdx.x * 4 + wid;      // ONE tile per wave (round-5 launch)
  if (tile >= T) return;
  {
    const int rbase = tile * 16;
    int rowA = rbase + lc; if (rowA >= N) rowA = N - 1;
    uint4 Ah[4];
    float xn2 = 0.f;
#pragma unroll
    for (int ks = 0; ks < 4; ++ks) {
      float f[8];
      if (BF) {
        uint4 v = ((const uint4*)((const u16*)xv + (size_t)rowA * D))[4 * ks + qg];
        f[0]=bflo(v.x); f[1]=bfhi(v.x); f[2]=bflo(v.y); f[3]=bfhi(v.y);
        f[4]=bflo(v.z); f[5]=bfhi(v.z); f[6]=bflo(v.w); f[7]=bfhi(v.w);
      } else {
        const float4* xr = (const float4*)((const float*)xv + (size_t)rowA * D);
        float4 f0 = xr[8 * ks + 2 * qg], f1 = xr[8 * ks + 2 * qg + 1];
        f[0]=f0.x; f[1]=f0.y; f[2]=f0.z; f[3]=f0.w;
        f[4]=f1.x; f[5]=f1.y; f[6]=f1.z; f[7]=f1.w;
      }
#pragma unroll
      for (int i = 0; i < 8; ++i) xn2 += f[i] * f[i];
      Ah[ks] = make_uint4(pkh(f[0],f[1]), pkh(f[2],f[3]),
                          pkh(f[4],f[5]), pkh(f[6],f[7]));
    }
    xn2 += __shfl_xor(xn2, 16);
    xn2 += __shfl_xor(xn2, 32);   // lane r holds ||x[rbase+r]||^2 (r = lane&15)

    f32x4 acc[8];
    const f32x4 zero = {0.f, 0.f, 0.f, 0.f};
#pragma unroll
    for (int t = 0; t < 8; ++t) acc[t] = zero;
#pragma unroll
    for (int ks = 0; ks < 4; ++ks) {
      f16x8 a = as_h8(Ah[ks]);
#pragma unroll
      for (int t = 0; t < 8; ++t) {
        f16x8 bh = as_h8(Wh[(t * 4 + ks) * 64 + lane]);
        acc[t] = __builtin_amdgcn_mfma_f32_16x16x32_f16(a, bh, acc[t], 0, 0, 0);
      }
    }

#pragma unroll
    for (int q = 0; q < 4; ++q) {
      const int row_off = qg * 4 + q;
      const int row = rbase + row_off;
      float xnq = fmaxf(sqrtf(__shfl(xn2, row_off)), MINNORM);
      float s2 = 0.f;
#pragma unroll
      for (int t = 0; t < 8; ++t) { float v = acc[t][q]; s2 += v * v; }
      s2 = rsum16(s2);
      float mxn = fmaxf(sqrtf(s2), MINNORM);
      float r = fast_tanh(mxn * frcp(xnq) * fast_artanh(xnq)) * frcp(mxn);
      float pn = r * mxn;
      if (pn > MAXNORM) { r *= MAXNORM * frcp(pn); pn = MAXNORM; }
      float h[8];
      float hn;
      if (bias_zero) {
#pragma unroll
        for (int t = 0; t < 8; ++t) h[t] = r * acc[t][q];
        hn = pn;
      } else {
        float xy = 0.f;
#pragma unroll
        for (int t = 0; t < 8; ++t) { h[t] = r * acc[t][q]; xy += h[t] * bfr[t]; }
        xy = rsum16(xy);
        float x2 = pn * pn;
        float ca = 1.f + 2.f * xy + y2;
        float cb = 1.f - x2;
        float id = frcp(fmaxf(1.f + 2.f * xy + x2 * y2, MINNORM));
        float s3 = 0.f;
#pragma unroll
        for (int t = 0; t < 8; ++t) { h[t] = (ca * h[t] + cb * bfr[t]) * id; s3 += h[t] * h[t]; }
        hn = fmaxf(sqrtf(rsum16(s3)), MINNORM);
      }
      float ps = (hn > MAXNORM) ? (MAXNORM * frcp(hn)) : 1.f;
      float np = fmaxf(hn * ps, MINNORM);
      float tsc = fast_artanh(np) * frcp(np) * ps;
      if (row < N) {
        // permuted store: positions lc*8..lc*8+7 = cols lc+16t, ONE uint4
        uint4 pk;
        pk.x = (u32)f2h(tsc * h[0]) | ((u32)f2h(tsc * h[1]) << 16);
        pk.y = (u32)f2h(tsc * h[2]) | ((u32)f2h(tsc * h[3]) << 16);
        pk.z = (u32)f2h(tsc * h[4]) | ((u32)f2h(tsc * h[5]) << 16);
        pk.w = (u32)f2h(tsc * h[6]) | ((u32)f2h(tsc * h[7]) << 16);
        *(uint4*)(xt + (size_t)row * D + lc * 8) = pk;
      }
    }
  }
}

extern "C" __global__ __launch_bounds__(256)
void OriginHyperbolicGraphConvolution_38628935860614_kernel(
    const void* x, const void* W, const void* b, u16* xt, int* btot, int N) {
  __shared__ uint4 Wh[2048];   // 32 KB (single fp16 plane)
  if (blockIdx.x == 0)         // fold btot zeroing here (no k0 launch)
    for (int i = threadIdx.x; i < MAXNB; i += 256) btot[i] = 0;
  if (detect_bf16((const u32*)x)) k1_body<true >(x, W, b, xt, N, Wh);
  else                            k1_body<false>(x, W, b, xt, N, Wh);
}

// ====== ksA: SINGLE edge pass: chunk-local counting sort -> chunk-major ebuck ======
// Reads ei+ew once, LDS counting-sorts by coarse bucket, writes records
// chunk-major (fully coalesced), writes the per-chunk u16 bucket-offset row,
// and accumulates per-bucket totals via fire-and-forget global atomics.
// Record: x = src(17b)|dstin(7b)<<17, y = w bits.
extern "C" __global__ __launch_bounds__(256) void ksA(
    const int* ei, const void* ew, uint2* ebuck, u16* soffs, int* btot,
    int E, int N, int nb) {
  __shared__ int   hist[MAXNB];        // 4 KB
  __shared__ int   sArr[MAXNB + 1];    // 4 KB
  __shared__ int   psum[256];          // 1 KB
  __shared__ uint2 recs[CHUNK];        // 16 KB
  const bool i64 = detect_i64(ei);
  const bool bf  = detect_bf16((const u32*)ew);
  const int tid   = threadIdx.x;
  const int cbase = blockIdx.x * CHUNK;

  for (int i = tid; i < MAXNB; i += 256) hist[i] = 0;
  __syncthreads();

  int bkt[8], rank[8]; u32 px[8], wb[8]; bool val[8];
#pragma unroll
  for (int r = 0; r < 8; ++r) {
    const int e = cbase + r * 256 + tid;
    val[r] = false;
    if (e < E) {
      int dst, src;
      if (i64) {
        dst = (int)((const uint2*)ei)[(size_t)e].x;
        src = (int)((const uint2*)ei)[(size_t)E + e].x;
      } else {
        dst = ei[e]; src = ei[(size_t)E + e];
      }
      if ((unsigned)dst < (unsigned)N && (unsigned)src < (unsigned)N) {
        val[r] = true;
        bkt[r] = dst >> BSH;
        px[r]  = (u32)src | ((u32)(dst & ((1 << BSH) - 1)) << 17);
        float w;
        if (bf) w = bf2f(((const u16*)ew)[e]); else w = ((const float*)ew)[e];
        wb[r] = __float_as_uint(w);
        rank[r] = atomicAdd(&hist[bkt[r]], 1);
      }
    }
  }
  __syncthreads();

  // exclusive scan of hist -> sArr (256 threads x 4 bins)
  const int g0 = tid * 4;
  int loc[4], ts = 0;
#pragma unroll
  for (int i = 0; i < 4; ++i) { loc[i] = ts; ts += hist[g0 + i]; }
  psum[tid] = ts; __syncthreads();
#pragma unroll
  for (int off = 1; off < 256; off <<= 1) {
    int t = (tid >= off) ? psum[tid - off] : 0;
    __syncthreads();
    psum[tid] += t;
    __syncthreads();
  }
  const int excl = psum[tid] - ts;
#pragma unroll
  for (int i = 0; i < 4; ++i) sArr[g0 + i] = excl + loc[i];
  if (tid == 255) sArr[MAXNB] = psum[255];
  __syncthreads();

  // place into LDS in bucket-sorted order
#pragma unroll
  for (int r = 0; r < 8; ++r) if (val[r])
    recs[sArr[bkt[r]] + rank[r]] = make_uint2(px[r], wb[r]);
  __syncthreads();

  const int vcnt = sArr[MAXNB];
  // coalesced chunk-major write + per-chunk offset row + bucket totals
  for (int i = tid; i < vcnt; i += 256) ebuck[(size_t)cbase + i] = recs[i];
  u16* so = soffs + (size_t)blockIdx.x * (nb + 1);
  for (int b = tid; b <= nb; b += 256) so[b] = (u16)sArr[b];
  for (int b = tid; b < nb; b += 256) {
    const int len = sArr[b + 1] - sArr[b];
    if (len) atomicAdd(&btot[b], len);
  }
}

// ====== ks3: gather bucket's runs -> LDS -> node-sort -> esrt + offs2 ======
// Block per bucket. Computes its own exclusive prefix over btot (L2-resident).
// Phase 1: pull this bucket's ~2.6-record runs from all chunks into 40 KB LDS
// staging while node-histogramming. Phase 2: 128-scan -> offs2[node] =
// (start, count). Phase 3: scatter LDS -> esrt (L2-resident window), stripping
// dstin. Fallback (> SCAP2): two direct passes.
extern "C" __global__ __launch_bounds__(256) void ks3(
    const uint2* ebuck, const u16* soffs, const int* btot,
    uint2* esrt, uint2* offs2, int N, int nb, int nchunks) {
  __shared__ uint2 stage[SCAP2];       // 40 KB
  __shared__ int red[256];
  __shared__ int hist[128], sc[128], cur[128];
  __shared__ int lcur;
  const int tid = threadIdx.x;
  const int b = blockIdx.x;

  // exclusive prefix of btot over [0, b)
  int part = 0;
  for (int i = tid; i < b; i += 256) part += btot[i];
  red[tid] = part;
  if (tid < 128) hist[tid] = 0;
  if (tid == 0) lcur = 0;
  __syncthreads();
#pragma unroll
  for (int off = 128; off; off >>= 1) {
    if (tid < off) red[tid] += red[tid + off];
    __syncthreads();
  }
  const int s0  = red[0];
  const int cnt = btot[b];
  const int node0 = b << BSH;

  const bool fit = (cnt <= SCAP2);
  if (fit) {
    for (int c = tid; c < nchunks; c += 256) {
      const u16* so = soffs + (size_t)c * (nb + 1) + b;
      const int a = so[0], e = so[1];
      if (e > a) {
        const int base = atomicAdd(&lcur, e - a);
        for (int j = a; j < e; ++j) {
          const uint2 r = ebuck[(size_t)c * CHUNK + j];
          stage[base + (j - a)] = r;
          atomicAdd(&hist[(r.x >> 17) & 127], 1);
        }
      }
    }
  } else {
    for (int c = tid; c < nchunks; c += 256) {
      const u16* so = soffs + (size_t)c * (nb + 1) + b;
      for (int j = so[0]; j < so[1]; ++j)
        atomicAdd(&hist[(ebuck[(size_t)c * CHUNK + j].x >> 17) & 127], 1);
    }
  }
  __syncthreads();

  int v = 0;
  if (tid < 128) { v = hist[tid]; sc[tid] = v; }
  __syncthreads();
#pragma unroll
  for (int off = 1; off < 128; off <<= 1) {
    int t = (tid < 128 && tid >= off) ? sc[tid - off] : 0;
    __syncthreads();
    if (tid < 128) sc[tid] += t;
    __syncthreads();
  }
  if (tid < 128) {
    const int st = sc[tid] - v;
    cur[tid] = st;
    const int node = node0 + tid;
    if (node < N) offs2[node] = make_uint2((u32)(s0 + st), (u32)v);
  }
  __syncthreads();

  if (fit) {
    for (int i = tid; i < cnt; i += 256) {
      const uint2 r = stage[i];
      const int d = atomicAdd(&cur[(r.x >> 17) & 127], 1);
      esrt[s0 + d] = make_uint2(r.x & 0x1FFFFu, r.y);
    }
  } else {
    for (int c = tid; c < nchunks; c += 256) {
      const u16* so = soffs + (size_t)c * (nb + 1) + b;
      for (int j = so[0]; j < so[1]; ++j) {
        const uint2 r = ebuck[(size_t)c * CHUNK + j];
        const int d = atomicAdd(&cur[(r.x >> 17) & 127], 1);
        esrt[s0 + d] = make_uint2(r.x & 0x1FFFFu, r.y);
      }
    }
  }
}

// ====== kagg: gather-aggregate per node + fused finalize ======
// Wave per node, register accumulation, wave-uniform s_load edge records,
// 16-deep gather ILP. xt is fp16 PERMUTED (pos p = (c&15)*8 + (c>>4));
// accumulation + finalize are permutation-invariant; the final store
// unpermutes via 4 shfls (lane l needs true cols 2l, 2l+1).
extern "C" __global__ __launch_bounds__(256) void kagg(
    const uint2* offs2, const uint2* esrt, const u16* xt,
    void* out, const void* xdet, int N) {
  const bool bf = detect_bf16((const u32*)xdet);
  const int lane = threadIdx.x & 63;
  const int node = blockIdx.x * 4 + (threadIdx.x >> 6);
  if (node >= N) return;
  const uint2 oo = offs2[node];
  const int s0  = __builtin_amdgcn_readfirstlane((int)oo.x);
  const int cnt = __builtin_amdgcn_readfirstlane((int)oo.y);
  const uint2* ep = esrt + s0;
  const u32* xtw = (const u32*)xt;
  float a0 = 0.f, a1 = 0.f;      // permuted positions 2*lane, 2*lane+1
  int i = 0;
  for (; i + 16 <= cnt; i += 16) {
    uint2 e[16]; u32 u[16];
#pragma unroll
    for (int k = 0; k < 16; ++k) e[k] = ep[i + k];            // uniform (s_load)
#pragma unroll
    for (int k = 0; k < 16; ++k) u[k] = xtw[(e[k].x << 6) | lane];  // 16 in flight
#pragma unroll
    for (int k = 0; k < 16; ++k) {
      const float w = __uint_as_float(e[k].y);
      U2H c; c.u = u[k];
      a0 += w * (float)c.h[0];
      a1 += w * (float)c.h[1];
    }
  }
  for (; i + 4 <= cnt; i += 4) {
    uint2 e[4]; u32 u[4];
#pragma unroll
    for (int k = 0; k < 4; ++k) e[k] = ep[i + k];
#pragma unroll
    for (int k = 0; k < 4; ++k) u[k] = xtw[(e[k].x << 6) | lane];
#pragma unroll
    for (int k = 0; k < 4; ++k) {
      const float w = __uint_as_float(e[k].y);
      U2H c; c.u = u[k];
      a0 += w * (float)c.h[0];
      a1 += w * (float)c.h[1];
    }
  }
  for (; i < cnt; ++i) {
    const uint2 e = ep[i];
    const u32 u = xtw[(e.x << 6) | lane];
    const float w = __uint_as_float(e.y);
    U2H c; c.u = u;
    a0 += w * (float)c.h[0];
    a1 += w * (float)c.h[1];
  }
  // finalize: expmap0 -> proj -> logmap0 -> relu -> expmap0 -> proj
  // (all permutation-invariant: norms via wsum, elementwise scales/relu)
  float n = fmaxf(sqrtf(wsum(a0 * a0 + a1 * a1)), MINNORM);
  float tn = fast_tanh(n);
  float m = tn * frcp(n);
  if (tn > MAXNORM) { m *= MAXNORM * frcp(tn); tn = MAXNORM; }
  float nn = fmaxf(tn, MINNORM);
  m *= fast_artanh(nn) * frcp(nn);
  float tA = fmaxf(m * a0, 0.f), tB = fmaxf(m * a1, 0.f);
  float nr = fmaxf(sqrtf(wsum(tA * tA + tB * tB)), MINNORM);
  float t2 = fast_tanh(nr);
  float m2 = t2 * frcp(nr);
  if (t2 > MAXNORM) m2 *= MAXNORM * frcp(t2);
  float oA = m2 * tA, oB = m2 * tB;   // values for permuted positions 2l, 2l+1
  // unpermute: true col 2l lives at pos p0=(l&7)*16+(l>>3) -> lane p0>>1,
  // elem p0&1; true col 2l+1 at p0+8 -> lane+4, same elem. (lane-verified)
  const int ls = (lane & 7) * 8 + (lane >> 4);
  const int el = (lane >> 3) & 1;
  const float A0 = __shfl(oA, ls),     B0 = __shfl(oB, ls);
  const float A1 = __shfl(oA, ls + 4), B1 = __shfl(oB, ls + 4);
  const float v0 = el ? B0 : A0;
  const float v1 = el ? B1 : A1;
  if (bf) {
    // bf16 output (RNE)
    u32 ua = __float_as_uint(v0), ub = __float_as_uint(v1);
    u32 ra = (ua + 0x7fffu + ((ua >> 16) & 1u)) >> 16;
    u32 rb = (ub + 0x7fffu + ((ub >> 16) & 1u)) >> 16;
    ((u32*)out)[(size_t)node * 64 + lane] = ra | (rb << 16);
  } else {
    ((float2*)out)[(size_t)node * 64 + lane] = make_float2(v0, v1);
  }
}

extern "C" void kernel_launch(void* const* d_in, const int* in_sizes, int n_in,
                              void* d_out, int out_size, void* d_ws, size_t ws_size,
                              hipStream_t stream) {
  const void* x    = d_in[0];
  const void* W    = d_in[1];
  const void* bias = d_in[2];
  const int*  ei   = (const int*)d_in[3];
  const void* ew   = d_in[4];
  const int N = in_sizes[0] / D;
  const int E = in_sizes[4];
  const int nchunks = (E + CHUNK - 1) / CHUNK;
  const int nb      = (N + (1 << BSH) - 1) >> BSH;

  char* ws = (char*)d_ws;
  size_t off = 0;
  auto carve = [&](size_t bytes) { char* p = ws + off; off = (off + bytes + 255) & ~(size_t)255; return p; };
  u16*   xt    = (u16*)  carve((size_t)N * D * sizeof(u16));               // 25.6 MB
  uint2* ebuck = (uint2*)carve((size_t)nchunks * CHUNK * sizeof(uint2));   // 12.8 MB
  uint2* esrt  = (uint2*)carve((size_t)E * sizeof(uint2));                 // 12.8 MB
  u16*   soffs = (u16*)  carve((size_t)nchunks * (nb + 1) * sizeof(u16));  // 1.2 MB
  uint2* offs2 = (uint2*)carve((size_t)N * sizeof(uint2));                 // 0.8 MB
  int*   btot  = (int*)  carve((size_t)MAXNB * sizeof(int));               // 4 KB

  const int T  = (N + 15) / 16;
  const int g1 = (T + 3) / 4;    // one tile per wave (round-5 launch semantics)

  OriginHyperbolicGraphConvolution_38628935860614_kernel<<<g1, 256, 0, stream>>>(
      x, W, bias, xt, btot, N);
  ksA <<<nchunks, 256, 0, stream>>>(ei, ew, ebuck, soffs, btot, E, N, nb);
  ks3 <<<nb, 256, 0, stream>>>(ebuck, soffs, btot, esrt, offs2, N, nb, nchunks);
  kagg<<<(N + 3) / 4, 256, 0, stream>>>(offs2, esrt, xt, d_out, x, N);
}

// Round 11
// 253.091 us; speedup vs baseline: 1.2282x; 1.0640x over previous
//
#include <hip/hip_runtime.h>
#include <math.h>

#define D 128
#define MAXNORM 0.996f            // (1 - 4e-3)/sqrt(c), c = 1
#define MINNORM 1e-15f
#define ATCLAMP (1.0f - 1e-7f)

#define CHUNK 2048                // edges per sort block (8 per thread)
#define BSH   7                   // 128 nodes per bucket
#define MAXNB 1024                // supports N <= 131072 (problem: N = 100000)
#define SCAP2 5120                // ks3 LDS staging records (mean ~2046/bucket)
#define CAP   4096                // fixed esrt slot per bucket (2x mean load)
#define TCAP  (1 << 20)           // tail region records (overflow spill)

typedef unsigned int   u32;
typedef unsigned short u16;

typedef __attribute__((ext_vector_type(8))) _Float16 f16x8;
typedef __attribute__((ext_vector_type(2))) __fp16   h2raw;   // builtin return type
typedef __attribute__((ext_vector_type(4))) float f32x4;

__device__ __forceinline__ float wsum(float v) {
#pragma unroll
  for (int m = 32; m; m >>= 1) v += __shfl_xor(v, m);
  return v;
}
// 16-lane reduction (stays within a lane&48 group) — matches MFMA C-layout rows
__device__ __forceinline__ float rsum16(float v) {
#pragma unroll
  for (int m = 1; m <= 8; m <<= 1) v += __shfl_xor(v, m);
  return v;
}

__device__ __forceinline__ float frcp(float x) { return __builtin_amdgcn_rcpf(x); }

// fast artanh for x in [0, 1-1e-7]
__device__ __forceinline__ float fast_artanh(float x) {
  x = fminf(x, ATCLAMP);
  return 0.5f * __logf((1.0f + x) * frcp(1.0f - x));
}
// fast tanh for z >= 0
__device__ __forceinline__ float fast_tanh(float z) {
  float t = __expf(-2.0f * z);
  return (1.0f - t) * frcp(1.0f + t);
}

__device__ __forceinline__ float bflo(u32 u) { return __uint_as_float(u << 16); }
__device__ __forceinline__ float bfhi(u32 u) { return __uint_as_float(u & 0xffff0000u); }
__device__ __forceinline__ float bf2f(u16 h) { return __uint_as_float(((u32)h) << 16); }

// pack 2 f32 -> 2 f16 (RTZ, 1 instr v_cvt_pkrtz_f16_f32) — used for MFMA fragments
union H2U { h2raw h; u32 u; };
__device__ __forceinline__ u32 pkh(float a, float b) {
  H2U c; c.h = __builtin_amdgcn_cvt_pkrtz(a, b); return c.u;
}
union U2H { u32 u; _Float16 h[2]; };
union U4H8 { uint4 u; f16x8 h; };
__device__ __forceinline__ f16x8 as_h8(uint4 v) { U4H8 c; c.u = v; return c.h; }
__device__ __forceinline__ u16 f2h(float f) {        // f32 -> f16 bits (RNE)
  _Float16 h = (_Float16)f; return *(u16*)&h;
}

// ---- runtime dtype detection (wave-uniform; call before any divergence) ----
__device__ __forceinline__ bool detect_bf16(const u32* p) {
  float lo = fabsf(bflo(p[threadIdx.x & 63]));
  return (bool)__all(lo < 1.0f);
}
__device__ __forceinline__ bool detect_i64(const int* p) {
  return (bool)__all(p[2 * (threadIdx.x & 63) + 1] == 0);
}

// ====== K1 body: MFMA mobius_matvec + proj + mobius_add(bias) + proj + logmap0 ======
// FP16 compute plane (r8/9), permuted xt store (r9), one-tile-per-wave exit-and-
// refill launch (r10, verified: K1 82 -> <67 us). 32 KB LDS single W plane.
// C layout (m89-verified): col = lane&15, row = (lane>>4)*4 + reg.
// xt layout: true col c at u16 position (c&15)*8 + (c>>4) -> one uint4/lane/row.
template<bool BF>
__device__ __forceinline__ void k1_body(const void* xv, const void* Wv,
                                        const void* bv, u16* xt, int N,
                                        uint4* Wh) {
  const int tid  = threadIdx.x;
  const int lane = tid & 63;
  const int wid  = tid >> 6;
  const int qg   = lane >> 4;   // k-block group 0..3
  const int lc   = lane & 15;   // col within 16-wide tile

  // stage W in fragment order (fp16): slot = (t*4+ks)*64 + l holds
  // W[(l&15)+16t, 32ks+8(l>>4) .. +8] as 8 fp16 (16B)
  for (int slot = tid; slot < 2048; slot += 256) {
    const int l = slot & 63, frag = slot >> 6;
    const int t = frag >> 2, ks = frag & 3;
    const int j  = (l & 15) + 16 * t;
    const int k0 = 32 * ks + 8 * (l >> 4);
    float f[8];
    if (BF) {
      uint4 v = ((const uint4*)Wv)[j * 16 + (k0 >> 3)];
      f[0] = bflo(v.x); f[1] = bfhi(v.x); f[2] = bflo(v.y); f[3] = bfhi(v.y);
      f[4] = bflo(v.z); f[5] = bfhi(v.z); f[6] = bflo(v.w); f[7] = bfhi(v.w);
    } else {
      const float* Wf = (const float*)Wv;
      float4 f0 = *(const float4*)(Wf + (size_t)j * D + k0);
      float4 f1 = *(const float4*)(Wf + (size_t)j * D + k0 + 4);
      f[0]=f0.x; f[1]=f0.y; f[2]=f0.z; f[3]=f0.w;
      f[4]=f1.x; f[5]=f1.y; f[6]=f1.z; f[7]=f1.w;
    }
    Wh[slot] = make_uint4(pkh(f[0],f[1]), pkh(f[2],f[3]),
                          pkh(f[4],f[5]), pkh(f[6],f[7]));
  }

  // hyp_bias fragment: bfr[t] = proj(expmap0(b))[lc + 16t]
  float bfr[8];
  float nb2 = 0.f;
#pragma unroll
  for (int t = 0; t < 8; ++t) {
    float v = BF ? bf2f(((const u16*)bv)[lc + 16 * t])
                 : ((const float*)bv)[lc + 16 * t];
    bfr[t] = v; nb2 += v * v;
  }
  nb2 = rsum16(nb2);
  float y2;
  {
    float nb = fmaxf(sqrtf(nb2), MINNORM);
    float s  = fast_tanh(nb) * frcp(nb);
    float n1 = s * nb;
    if (n1 > MAXNORM) s *= MAXNORM * frcp(n1);
#pragma unroll
    for (int t = 0; t < 8; ++t) bfr[t] *= s;
    y2 = s * s * nb2;
  }
  const bool bias_zero = (y2 == 0.0f);

  __syncthreads();

  const int T = (N + 15) >> 4;
  const int tile = blockIdx.x * 4 + wid;      // ONE tile per wave
  if (tile >= T) return;
  {
    const int rbase = tile * 16;
    int rowA = rbase + lc; if (rowA >= N) rowA = N - 1;
    uint4 Ah[4];
    float xn2 = 0.f;
#pragma unroll
    for (int ks = 0; ks < 4; ++ks) {
      float f[8];
      if (BF) {
        uint4 v = ((const uint4*)((const u16*)xv + (size_t)rowA * D))[4 * ks + qg];
        f[0]=bflo(v.x); f[1]=bfhi(v.x); f[2]=bflo(v.y); f[3]=bfhi(v.y);
        f[4]=bflo(v.z); f[5]=bfhi(v.z); f[6]=bflo(v.w); f[7]=bfhi(v.w);
      } else {
        const float4* xr = (const float4*)((const float*)xv + (size_t)rowA * D);
        float4 f0 = xr[8 * ks + 2 * qg], f1 = xr[8 * ks + 2 * qg + 1];
        f[0]=f0.x; f[1]=f0.y; f[2]=f0.z; f[3]=f0.w;
        f[4]=f1.x; f[5]=f1.y; f[6]=f1.z; f[7]=f1.w;
      }
#pragma unroll
      for (int i = 0; i < 8; ++i) xn2 += f[i] * f[i];
      Ah[ks] = make_uint4(pkh(f[0],f[1]), pkh(f[2],f[3]),
                          pkh(f[4],f[5]), pkh(f[6],f[7]));
    }
    xn2 += __shfl_xor(xn2, 16);
    xn2 += __shfl_xor(xn2, 32);   // lane r holds ||x[rbase+r]||^2 (r = lane&15)

    f32x4 acc[8];
    const f32x4 zero = {0.f, 0.f, 0.f, 0.f};
#pragma unroll
    for (int t = 0; t < 8; ++t) acc[t] = zero;
#pragma unroll
    for (int ks = 0; ks < 4; ++ks) {
      f16x8 a = as_h8(Ah[ks]);
#pragma unroll
      for (int t = 0; t < 8; ++t) {
        f16x8 bh = as_h8(Wh[(t * 4 + ks) * 64 + lane]);
        acc[t] = __builtin_amdgcn_mfma_f32_16x16x32_f16(a, bh, acc[t], 0, 0, 0);
      }
    }

#pragma unroll
    for (int q = 0; q < 4; ++q) {
      const int row_off = qg * 4 + q;
      const int row = rbase + row_off;
      float xnq = fmaxf(sqrtf(__shfl(xn2, row_off)), MINNORM);
      float s2 = 0.f;
#pragma unroll
      for (int t = 0; t < 8; ++t) { float v = acc[t][q]; s2 += v * v; }
      s2 = rsum16(s2);
      float mxn = fmaxf(sqrtf(s2), MINNORM);
      float r = fast_tanh(mxn * frcp(xnq) * fast_artanh(xnq)) * frcp(mxn);
      float pn = r * mxn;
      if (pn > MAXNORM) { r *= MAXNORM * frcp(pn); pn = MAXNORM; }
      float h[8];
      float hn;
      if (bias_zero) {
#pragma unroll
        for (int t = 0; t < 8; ++t) h[t] = r * acc[t][q];
        hn = pn;
      } else {
        float xy = 0.f;
#pragma unroll
        for (int t = 0; t < 8; ++t) { h[t] = r * acc[t][q]; xy += h[t] * bfr[t]; }
        xy = rsum16(xy);
        float x2 = pn * pn;
        float ca = 1.f + 2.f * xy + y2;
        float cb = 1.f - x2;
        float id = frcp(fmaxf(1.f + 2.f * xy + x2 * y2, MINNORM));
        float s3 = 0.f;
#pragma unroll
        for (int t = 0; t < 8; ++t) { h[t] = (ca * h[t] + cb * bfr[t]) * id; s3 += h[t] * h[t]; }
        hn = fmaxf(sqrtf(rsum16(s3)), MINNORM);
      }
      float ps = (hn > MAXNORM) ? (MAXNORM * frcp(hn)) : 1.f;
      float np = fmaxf(hn * ps, MINNORM);
      float tsc = fast_artanh(np) * frcp(np) * ps;
      if (row < N) {
        // permuted store: positions lc*8..lc*8+7 = cols lc+16t, ONE uint4
        uint4 pk;
        pk.x = (u32)f2h(tsc * h[0]) | ((u32)f2h(tsc * h[1]) << 16);
        pk.y = (u32)f2h(tsc * h[2]) | ((u32)f2h(tsc * h[3]) << 16);
        pk.z = (u32)f2h(tsc * h[4]) | ((u32)f2h(tsc * h[5]) << 16);
        pk.w = (u32)f2h(tsc * h[6]) | ((u32)f2h(tsc * h[7]) << 16);
        *(uint4*)(xt + (size_t)row * D + lc * 8) = pk;
      }
    }
  }
}

// ====== ksA body: chunk-local counting sort -> chunk-major ebuck + soffs ======
// (round-10 verified, minus the 611K btot global atomics.) LDS is aliased into
// the K1 W-plane (25.6 KB of 32 KB): recs[2048] | hist[1024] | sArr[1025] |
// psum[256]. Record: x = src(17b)|dstin(7b)<<17, y = w bits.
__device__ __forceinline__ void ksA_body(
    const int* ei, const void* ew, uint2* ebuck, u16* soffs,
    int E, int N, int nb, int chunk, uint4* lds) {
  uint2* recs = (uint2*)lds;                 // 16 KB  (bytes 0..16383)
  int*   hist = (int*)(lds + 1024);          // 4 KB   (16384..20479)
  int*   sArr = hist + MAXNB;                // 4.1 KB (20480..24579)
  int*   psum = sArr + MAXNB + 1;            // 1 KB   (24580..25603)
  const bool i64 = detect_i64(ei);
  const bool bf  = detect_bf16((const u32*)ew);
  const int tid   = threadIdx.x;
  const int cbase = chunk * CHUNK;

  for (int i = tid; i < MAXNB; i += 256) hist[i] = 0;
  __syncthreads();

  int bkt[8], rank[8]; u32 px[8], wb[8]; bool val[8];
#pragma unroll
  for (int r = 0; r < 8; ++r) {
    const int e = cbase + r * 256 + tid;
    val[r] = false;
    if (e < E) {
      int dst, src;
      if (i64) {
        dst = (int)((const uint2*)ei)[(size_t)e].x;
        src = (int)((const uint2*)ei)[(size_t)E + e].x;
      } else {
        dst = ei[e]; src = ei[(size_t)E + e];
      }
      if ((unsigned)dst < (unsigned)N && (unsigned)src < (unsigned)N) {
        val[r] = true;
        bkt[r] = dst >> BSH;
        px[r]  = (u32)src | ((u32)(dst & ((1 << BSH) - 1)) << 17);
        float w;
        if (bf) w = bf2f(((const u16*)ew)[e]); else w = ((const float*)ew)[e];
        wb[r] = __float_as_uint(w);
        rank[r] = atomicAdd(&hist[bkt[r]], 1);
      }
    }
  }
  __syncthreads();

  // exclusive scan of hist -> sArr (256 threads x 4 bins)
  const int g0 = tid * 4;
  int loc[4], ts = 0;
#pragma unroll
  for (int i = 0; i < 4; ++i) { loc[i] = ts; ts += hist[g0 + i]; }
  psum[tid] = ts; __syncthreads();
#pragma unroll
  for (int off = 1; off < 256; off <<= 1) {
    int t = (tid >= off) ? psum[tid - off] : 0;
    __syncthreads();
    psum[tid] += t;
    __syncthreads();
  }
  const int excl = psum[tid] - ts;
#pragma unroll
  for (int i = 0; i < 4; ++i) sArr[g0 + i] = excl + loc[i];
  if (tid == 255) sArr[MAXNB] = psum[255];
  __syncthreads();

  // place into LDS in bucket-sorted order
#pragma unroll
  for (int r = 0; r < 8; ++r) if (val[r])
    recs[sArr[bkt[r]] + rank[r]] = make_uint2(px[r], wb[r]);
  __syncthreads();

  const int vcnt = sArr[MAXNB];
  // coalesced chunk-major write + per-chunk offset row
  for (int i = tid; i < vcnt; i += 256) ebuck[(size_t)cbase + i] = recs[i];
  u16* so = soffs + (size_t)chunk * (nb + 1);
  for (int b = tid; b <= nb; b += 256) so[b] = (u16)sArr[b];
}

// ====== fused K1 + ksA: independent stages share one dispatch ======
// Blocks [0, nk1) run K1 (one 16-row tile per wave, exit); blocks [nk1, ..)
// run ksA on chunk = blockIdx - nk1. MFMA-heavy K1 waves and gather-heavy ksA
// waves co-schedule on separate pipes (m114); removes one full serialization.
extern "C" __global__ __launch_bounds__(256)
void OriginHyperbolicGraphConvolution_38628935860614_kernel(
    const void* x, const void* W, const void* b, u16* xt,
    const int* ei, const void* ew, uint2* ebuck, u16* soffs, int* tailcur,
    int N, int E, int nb, int nk1) {
  __shared__ uint4 Wh[2048];   // 32 KB: K1 W-plane / ksA sort buffers (aliased)
  if (blockIdx.x == 0 && threadIdx.x == 0) *tailcur = 0;
  if ((int)blockIdx.x < nk1) {
    if (detect_bf16((const u32*)x)) k1_body<true >(x, W, b, xt, N, Wh);
    else                            k1_body<false>(x, W, b, xt, N, Wh);
  } else {
    ksA_body(ei, ew, ebuck, soffs, E, N, nb, (int)blockIdx.x - nk1, Wh);
  }
}

// ====== ks3: gather bucket's runs -> LDS -> node-sort -> esrt slot + offs2 ======
// Block per bucket. NO global prefix: bucket b owns fixed slot [b*CAP, b*CAP+CAP)
// in esrt (gaps are fine — kagg uses (start,count)). Pre-pass sums the soffs
// column for cnt (L2-resident). Overflow cnt>CAP claims tail via ONE atomic.
// Phase 1: pull runs into 40 KB LDS staging + node-histogram. Phase 2: 128-scan
// -> offs2[node] = (start, count). Phase 3: scatter LDS -> esrt slot, stripping
// dstin. Fallback (cnt > SCAP2): two direct passes.
extern "C" __global__ __launch_bounds__(256) void ks3(
    const uint2* ebuck, const u16* soffs, uint2* esrt, uint2* offs2,
    int* tailcur, int N, int nb, int nchunks) {
  __shared__ uint2 stage[SCAP2];       // 40 KB
  __shared__ int red[256];
  __shared__ int hist[128], sc[128], cur[128];
  __shared__ int lcur;
  __shared__ u32 sbase;
  const int tid = threadIdx.x;
  const int b = blockIdx.x;
  const int node0 = b << BSH;

  // pre-pass: cnt = sum over chunks of this bucket's run lengths
  int myc = 0;
  for (int c = tid; c < nchunks; c += 256) {
    const u16* so = soffs + (size_t)c * (nb + 1) + b;
    myc += (int)so[1] - (int)so[0];
  }
  red[tid] = myc;
  if (tid < 128) hist[tid] = 0;
  if (tid == 0) lcur = 0;
  __syncthreads();
#pragma unroll
  for (int off = 128; off; off >>= 1) {
    if (tid < off) red[tid] += red[tid + off];
    __syncthreads();
  }
  const int cnt = red[0];
  if (tid == 0)
    sbase = (cnt <= CAP) ? (u32)((size_t)b * CAP)
                         : (u32)((size_t)nb * CAP + (u32)atomicAdd(tailcur, cnt));
  __syncthreads();
  const u32 base = sbase;

  const bool fit = (cnt <= SCAP2);
  if (fit) {
    for (int c = tid; c < nchunks; c += 256) {
      const u16* so = soffs + (size_t)c * (nb + 1) + b;
      const int a = so[0], e = so[1];
      if (e > a) {
        const int sb = atomicAdd(&lcur, e - a);
        for (int j = a; j < e; ++j) {
          const uint2 r = ebuck[(size_t)c * CHUNK + j];
          stage[sb + (j - a)] = r;
          atomicAdd(&hist[(r.x >> 17) & 127], 1);
        }
      }
    }
  } else {
    for (int c = tid; c < nchunks; c += 256) {
      const u16* so = soffs + (size_t)c * (nb + 1) + b;
      for (int j = so[0]; j < so[1]; ++j)
        atomicAdd(&hist[(ebuck[(size_t)c * CHUNK + j].x >> 17) & 127], 1);
    }
  }
  __syncthreads();

  int v = 0;
  if (tid < 128) { v = hist[tid]; sc[tid] = v; }
  __syncthreads();
#pragma unroll
  for (int off = 1; off < 128; off <<= 1) {
    int t = (tid < 128 && tid >= off) ? sc[tid - off] : 0;
    __syncthreads();
    if (tid < 128) sc[tid] += t;
    __syncthreads();
  }
  if (tid < 128) {
    const int st = sc[tid] - v;
    cur[tid] = st;
    const int node = node0 + tid;
    if (node < N) offs2[node] = make_uint2(base + (u32)st, (u32)v);
  }
  __syncthreads();

  if (fit) {
    for (int i = tid; i < cnt; i += 256) {
      const uint2 r = stage[i];
      const int d = atomicAdd(&cur[(r.x >> 17) & 127], 1);
      esrt[(size_t)base + d] = make_uint2(r.x & 0x1FFFFu, r.y);
    }
  } else {
    for (int c = tid; c < nchunks; c += 256) {
      const u16* so = soffs + (size_t)c * (nb + 1) + b;
      for (int j = so[0]; j < so[1]; ++j) {
        const uint2 r = ebuck[(size_t)c * CHUNK + j];
        const int d = atomicAdd(&cur[(r.x >> 17) & 127], 1);
        esrt[(size_t)base + d] = make_uint2(r.x & 0x1FFFFu, r.y);
      }
    }
  }
}

// ====== kagg: gather-aggregate per node + fused finalize (round-10 verified) ======
// Wave per node, register accumulation, wave-uniform s_load edge records,
// 16-deep gather ILP. xt is fp16 PERMUTED (pos p = (c&15)*8 + (c>>4));
// accumulation + finalize are permutation-invariant; the final store
// unpermutes via 4 shfls (lane l needs true cols 2l, 2l+1).
extern "C" __global__ __launch_bounds__(256) void kagg(
    const uint2* offs2, const uint2* esrt, const u16* xt,
    void* out, const void* xdet, int N) {
  const bool bf = detect_bf16((const u32*)xdet);
  const int lane = threadIdx.x & 63;
  const int node = blockIdx.x * 4 + (threadIdx.x >> 6);
  if (node >= N) return;
  const uint2 oo = offs2[node];
  const int s0  = __builtin_amdgcn_readfirstlane((int)oo.x);
  const int cnt = __builtin_amdgcn_readfirstlane((int)oo.y);
  const uint2* ep = esrt + s0;
  const u32* xtw = (const u32*)xt;
  float a0 = 0.f, a1 = 0.f;      // permuted positions 2*lane, 2*lane+1
  int i = 0;
  for (; i + 16 <= cnt; i += 16) {
    uint2 e[16]; u32 u[16];
#pragma unroll
    for (int k = 0; k < 16; ++k) e[k] = ep[i + k];            // uniform (s_load)
#pragma unroll
    for (int k = 0; k < 16; ++k) u[k] = xtw[(e[k].x << 6) | lane];  // 16 in flight
#pragma unroll
    for (int k = 0; k < 16; ++k) {
      const float w = __uint_as_float(e[k].y);
      U2H c; c.u = u[k];
      a0 += w * (float)c.h[0];
      a1 += w * (float)c.h[1];
    }
  }
  for (; i + 4 <= cnt; i += 4) {
    uint2 e[4]; u32 u[4];
#pragma unroll
    for (int k = 0; k < 4; ++k) e[k] = ep[i + k];
#pragma unroll
    for (int k = 0; k < 4; ++k) u[k] = xtw[(e[k].x << 6) | lane];
#pragma unroll
    for (int k = 0; k < 4; ++k) {
      const float w = __uint_as_float(e[k].y);
      U2H c; c.u = u[k];
      a0 += w * (float)c.h[0];
      a1 += w * (float)c.h[1];
    }
  }
  for (; i < cnt; ++i) {
    const uint2 e = ep[i];
    const u32 u = xtw[(e.x << 6) | lane];
    const float w = __uint_as_float(e.y);
    U2H c; c.u = u;
    a0 += w * (float)c.h[0];
    a1 += w * (float)c.h[1];
  }
  // finalize: expmap0 -> proj -> logmap0 -> relu -> expmap0 -> proj
  // (all permutation-invariant: norms via wsum, elementwise scales/relu)
  float n = fmaxf(sqrtf(wsum(a0 * a0 + a1 * a1)), MINNORM);
  float tn = fast_tanh(n);
  float m = tn * frcp(n);
  if (tn > MAXNORM) { m *= MAXNORM * frcp(tn); tn = MAXNORM; }
  float nn = fmaxf(tn, MINNORM);
  m *= fast_artanh(nn) * frcp(nn);
  float tA = fmaxf(m * a0, 0.f), tB = fmaxf(m * a1, 0.f);
  float nr = fmaxf(sqrtf(wsum(tA * tA + tB * tB)), MINNORM);
  float t2 = fast_tanh(nr);
  float m2 = t2 * frcp(nr);
  if (t2 > MAXNORM) m2 *= MAXNORM * frcp(t2);
  float oA = m2 * tA, oB = m2 * tB;   // values for permuted positions 2l, 2l+1
  // unpermute: true col 2l lives at pos p0=(l&7)*16+(l>>3) -> lane p0>>1,
  // elem p0&1; true col 2l+1 at p0+8 -> lane+4, same elem. (lane-verified)
  const int ls = (lane & 7) * 8 + (lane >> 4);
  const int el = (lane >> 3) & 1;
  const float A0 = __shfl(oA, ls),     B0 = __shfl(oB, ls);
  const float A1 = __shfl(oA, ls + 4), B1 = __shfl(oB, ls + 4);
  const float v0 = el ? B0 : A0;
  const float v1 = el ? B1 : A1;
  if (bf) {
    // bf16 output (RNE)
    u32 ua = __float_as_uint(v0), ub = __float_as_uint(v1);
    u32 ra = (ua + 0x7fffu + ((ua >> 16) & 1u)) >> 16;
    u32 rb = (ub + 0x7fffu + ((ub >> 16) & 1u)) >> 16;
    ((u32*)out)[(size_t)node * 64 + lane] = ra | (rb << 16);
  } else {
    ((float2*)out)[(size_t)node * 64 + lane] = make_float2(v0, v1);
  }
}

extern "C" void kernel_launch(void* const* d_in, const int* in_sizes, int n_in,
                              void* d_out, int out_size, void* d_ws, size_t ws_size,
                              hipStream_t stream) {
  const void* x    = d_in[0];
  const void* W    = d_in[1];
  const void* bias = d_in[2];
  const int*  ei   = (const int*)d_in[3];
  const void* ew   = d_in[4];
  const int N = in_sizes[0] / D;
  const int E = in_sizes[4];
  const int nchunks = (E + CHUNK - 1) / CHUNK;
  const int nb      = (N + (1 << BSH) - 1) >> BSH;

  char* ws = (char*)d_ws;
  size_t off = 0;
  auto carve = [&](size_t bytes) { char* p = ws + off; off = (off + bytes + 255) & ~(size_t)255; return p; };
  u16*   xt    = (u16*)  carve((size_t)N * D * sizeof(u16));                 // 25.6 MB
  uint2* ebuck = (uint2*)carve((size_t)nchunks * CHUNK * sizeof(uint2));     // 12.8 MB
  uint2* esrt  = (uint2*)carve(((size_t)nb * CAP + TCAP) * sizeof(uint2));   // 34 MB
  u16*   soffs = (u16*)  carve((size_t)nchunks * (nb + 1) * sizeof(u16));    // 1.2 MB
  uint2* offs2 = (uint2*)carve((size_t)N * sizeof(uint2));                   // 0.8 MB
  int*   tailcur = (int*)carve(256);

  const int T   = (N + 15) / 16;
  const int nk1 = (T + 3) / 4;    // K1 blocks (one tile per wave)

  OriginHyperbolicGraphConvolution_38628935860614_kernel<<<nk1 + nchunks, 256, 0, stream>>>(
      x, W, bias, xt, ei, ew, ebuck, soffs, tailcur, N, E, nb, nk1);
  ks3 <<<nb, 256, 0, stream>>>(ebuck, soffs, esrt, offs2, tailcur, N, nb, nchunks);
  kagg<<<(N + 3) / 4, 256, 0, stream>>>(offs2, esrt, xt, d_out, x, N);
}